// Round 11
// baseline (653.306 us; speedup 1.0000x reference)
//
#include <hip/hip_runtime.h>
#if __has_include(<hip/hip_bf16.h>)
#include <hip/hip_bf16.h>
#define HAVE_HIP_BF16 1
#endif

#define R 116
#define RP 120                     // padded Zc row stride (240B = 16B-aligned rows)
#define GZ 13920                   // RP*R: padded Zc graph size (elems)
#define BATCH 1024
#define NL 4
#define RR2 13456          // R*R (unpadded, for Z1)
#define EPSF 1e-5f
#define NZP_ELEM (BATCH * GZ)     // 14,254,080 (padded Zc)
#define NZ_ELEM (BATCH * RR2)     // 13,778,944 (Z1)
#define NX_ELEM (BATCH * R * 3)   //    356,352
#define LS 136                    // LDS row stride (bf16 elems)
#define XZS 2336                  // XZ/cw1p K-stride: 2320 padded to 73*32
#define NSH 8                     // stat shards (atomic contention divider)
#define STL 464                   // NL*R stats stride
#define NCHP 1740                 // GZ/8 uint4 chunks per padded graph (no row crossing)

typedef unsigned short ushort_t;
typedef __attribute__((ext_vector_type(8))) short bf16x8;
typedef __attribute__((ext_vector_type(4))) float f32x4;

__device__ __forceinline__ float bf2f(unsigned short u){
  union { unsigned int i; float f; } v; v.i = ((unsigned int)u) << 16; return v.f;
}
// f32 -> bf16 RTNE via OFFICIAL intrinsic (round-10 verified).  Hand-written
// v_cvt_pk asm remains QUARANTINED (rounds 5/8: absmax 1.41).
__device__ __forceinline__ unsigned short f2bf(float f){
#ifdef HAVE_HIP_BF16
  union { __hip_bfloat16 h; unsigned short u; } cv;
  cv.h = __float2bfloat16(f);
  return cv.u;
#else
  union { float ff; unsigned int i; } v; v.ff = f;
  return (unsigned short)((v.i + 0x7fffu + ((v.i >> 16) & 1u)) >> 16);
#endif
}
__device__ __forceinline__ float u2f_lo(unsigned w){
  union { unsigned i; float f; } v; v.i = w << 16; return v.f;
}
__device__ __forceinline__ float u2f_hi(unsigned w){
  union { unsigned i; float f; } v; v.i = w & 0xffff0000u; return v.f;
}
__device__ __forceinline__ float wsum(float v){
  #pragma unroll
  for (int o = 32; o > 0; o >>= 1) v += __shfl_xor(v, o, 64);
  return v;
}
__device__ __forceinline__ float wmaxr(float v){
  #pragma unroll
  for (int o = 32; o > 0; o >>= 1) v = fmaxf(v, __shfl_xor(v, o, 64));
  return v;
}

// ---------------- merged init: Zc-padded conv, cw1/aw2/ew pack, X copy, zeroing, out=cb2 ----------------
__global__ void k_init(const float* __restrict__ Zin, ushort_t* __restrict__ Zcp,
                       const float* __restrict__ Xin, float* __restrict__ Xc,
                       float* __restrict__ st, unsigned* __restrict__ xzw,
                       unsigned* __restrict__ z1g,
                       const float* __restrict__ aw2, const float* __restrict__ ew,
                       ushort_t* __restrict__ aw2p, ushort_t* __restrict__ ewp,
                       const float* __restrict__ cw1, ushort_t* __restrict__ cw1p,
                       const float* __restrict__ cb2, float* __restrict__ out)
{
  int idx = blockIdx.x * 256 + threadIdx.x;
  int stride = gridDim.x * 256;
  // Zc padded: chunk = 8 elems within one row (120%8==0); pad cols 116..119 = 0
  for (int i = idx; i < BATCH * NCHP; i += stride){
    int g = i / NCHP, ch = i - g * NCHP;
    int e0 = ch << 3, r = e0 / RP, c0 = e0 - r * RP;
    const float* zi = Zin + (size_t)g * RR2 + r * R + c0;   // 16B-aligned (all terms %4==0)
    float4 f0 = *(const float4*)zi;
    uint4 w;
    w.x = (unsigned)f2bf(f0.x) | ((unsigned)f2bf(f0.y) << 16);
    w.y = (unsigned)f2bf(f0.z) | ((unsigned)f2bf(f0.w) << 16);
    if (c0 == 112){ w.z = 0u; w.w = 0u; }                   // pad cols 116..119
    else {
      float4 f1 = *(const float4*)(zi + 4);
      w.z = (unsigned)f2bf(f1.x) | ((unsigned)f2bf(f1.y) << 16);
      w.w = (unsigned)f2bf(f1.z) | ((unsigned)f2bf(f1.w) << 16);
    }
    *(uint4*)(Zcp + (size_t)g * GZ + e0) = w;
  }
  for (int i = idx; i < 1024 * XZS; i += stride){
    int n = i / XZS, k = i - n * XZS;
    cw1p[i] = (k < 2320) ? f2bf(cw1[n*2320 + k]) : (ushort_t)0;
  }
  for (int i = idx; i < 4*128*128; i += stride){
    int l = i >> 14, rem = i & 16383, row = rem >> 7, col = rem & 127;
    ushort_t v = 0, w = 0;
    if (row < R && col < R){
      v = f2bf(aw2[l*RR2 + col*R + row]);   // aw2p[row][col] = aw2[col][row]  (aw2^T)
      w = f2bf(ew [l*RR2 + row*R + col]);   // ewp [row][col] = ew[row][col]
    }
    aw2p[i] = v;
    ewp [i] = w;
  }
  for (int i = idx; i < NX_ELEM; i += stride) Xc[i] = Xin[i];
  for (int i = idx; i < 15008; i += stride) st[i] = 0.f;
  for (int i = idx; i < BATCH*XZS/2; i += stride) xzw[i] = 0u;
  for (int i = idx; i < 736; i += stride) z1g[i] = 0u;   // guard: graph 1023 row-tail reads (<=2896B)
  for (int i = idx; i < 1024; i += stride){ out[2*i] = cb2[0]; out[2*i+1] = cb2[1]; }
}

// ==================================================================================
// Fused per-layer kernel.  Round-10 base + padded Zc (RP=120):
//   - every B'/E Z-fragment is ONE 16B-aligned dwordx4 (was 2x dwordx2)
//   - P0 chunks never cross a row: one coeff pair, uint4 everywhere
//   - pad cols provably harmless: contraction k>=116 multiplies zero aw2p/ewp/W
// ==================================================================================
__launch_bounds__(1024, 8)
__global__ void k_fused(float* __restrict__ Xc, ushort_t* __restrict__ Zc,
                        ushort_t* __restrict__ Z1, float* __restrict__ X1,
                        const float* __restrict__ aw1, const float* __restrict__ ab1,
                        const ushort_t* __restrict__ aw2p, const float* __restrict__ ab2,
                        const float* __restrict__ nw,  const float* __restrict__ nb,
                        const ushort_t* __restrict__ ewp,  const float* __restrict__ eb,
                        float* __restrict__ zsumS, float* __restrict__ zsqS,
                        float* __restrict__ xsumS, float* __restrict__ xsqS,
                        const float* __restrict__ geg, const float* __restrict__ geb,
                        const float* __restrict__ gng, const float* __restrict__ gnb,
                        const float* __restrict__ dnw, const float* __restrict__ dnb,
                        const float* __restrict__ dew, const float* __restrict__ deb,
                        ushort_t* __restrict__ XZ,
                        float* __restrict__ dnS, float* __restrict__ deS,
                        int layer, int with_attn)
{
  __shared__ __align__(16) ushort_t bA[128*LS];    // P, then M (row-major)
  __shared__ __align__(16) ushort_t bB[128*LS];    // padded-Z staging, then W, then E^T
  __shared__ float Ksm[3*R];
  __shared__ float ssm[R];
  __shared__ float xp[R*12];         // X-path partials; head aliased as BN coeffs in P0
  __shared__ float zps[128*2];       // per-row Z1 sum partials
  __shared__ float zpq[128*2];
  __shared__ float wsm[78];          // edge downsample weights
  __shared__ float xsred[3], xqred[3];
  __shared__ float zds[8], zqs[8];

  float* zcoA = xp;          // [R] BN coeff a for Z rows (dead before xp written)
  float* zcoC = xp + 116;
  float* xcoA = xp + 232;
  float* xcoC = xp + 348;
  ushort_t* bBlin = bB;      // padded-stride staged Z view ([r*RP + c])

  const int b    = blockIdx.x;
  const int tid  = threadIdx.x;
  const int lane = tid & 63;
  const int wave = tid >> 6;          // 16 waves
  const int qm   = lane & 15;
  const int quad = lane >> 4;
  const int tr   = wave & 7;
  const int tc0  = (wave >> 3) * 4;
  const int t_snap = layer;           // snapshot index for downsample outputs
  const int sh   = b & (NSH-1);

  ushort_t* Zb = Zc + (size_t)b * GZ;
  const ushort_t* Z1b = Z1 + (size_t)b * RR2;
  const float* ab2l = ab2 + layer * R;
  const float* ebl  = eb  + layer * R;
  const float* nwl  = nw  + layer * 9;
  const float* nbl  = nb  + layer * 3;
  const ushort_t* aw2l = aw2p + layer * 16384;
  const ushort_t* ewl  = ewp  + layer * 16384;

  const f32x4 vzero = {0.f, 0.f, 0.f, 0.f};

  // =============== Phase -1: per-row BN coeffs + wsm ===============
  if (tid < R){
    float a = 0.f, c = 0.f;
    if (layer > 0){
      const int pl = layer - 1;
      float ms = 0.f, qs = 0.f;
      #pragma unroll
      for (int s2 = 0; s2 < NSH; s2++){
        ms += zsumS[s2*STL + pl*R + tid];
        qs += zsqS [s2*STL + pl*R + tid];
      }
      const float cnt = (float)(BATCH * R);
      float m  = ms / cnt;
      float va = fmaxf(qs / cnt - m*m, 0.f);
      float rs = rsqrtf(va + EPSF);
      a = rs * geg[pl*R + tid];
      c = geb[pl*R + tid] - m * a;
    }
    zcoA[tid] = a; zcoC[tid] = c;
  } else if (tid >= 128 && tid < 128 + R){
    const int r = tid - 128;
    float a = 0.f, c = 0.f;
    if (layer > 0){
      const int pl = layer - 1;
      float ms = 0.f, qs = 0.f;
      #pragma unroll
      for (int s2 = 0; s2 < NSH; s2++){
        ms += xsumS[s2*STL + pl*R + r];
        qs += xsqS [s2*STL + pl*R + r];
      }
      const float cnt = (float)(BATCH * 3);
      float m  = ms / cnt;
      float va = fmaxf(qs / cnt - m*m, 0.f);
      float rs = rsqrtf(va + EPSF);
      a = rs * gng[pl*R + r];
      c = gnb[pl*R + r] - m * a;
    }
    xcoA[r] = a; xcoC[r] = c;
  } else if (tid >= 256 && tid < 256 + 78){
    wsm[tid - 256] = dew[t_snap*78 + (tid - 256)];
  }
  __syncthreads();   // ---- sync0 ----

  // =============== P0: padded Z stream (2-chunk unroll) + X rows + bA pad zero ===============
  {
    const int ch0 = tid;                 // always < NCHP (1740 > 1024)
    const int ch1 = tid + 1024;
    const bool hasB = (ch1 < NCHP);
    const int e0A = ch0 << 3;
    const int e0B = ch1 << 3;
    uint4 zcA = *(const uint4*)(Zb + e0A);
    uint4 zcB; if (hasB) zcB = *(const uint4*)(Zb + e0B);
    if (layer > 0){
      // Z1 is unpadded: 4x dword reads (always 4B-aligned); c0==112 tail reads are
      // finite neighbors (guard/next-row/Xc) and the results are overwritten with 0.
      const int rA = e0A / RP, cA0 = e0A - rA*RP;
      const int rB = hasB ? (e0B / RP) : 0, cB0 = hasB ? (e0B - rB*RP) : 0;
      const ushort_t* z1pA = Z1b + rA*R + cA0;
      const ushort_t* z1pB = Z1b + rB*R + cB0;
      unsigned z1A[4], z1B[4];
      #pragma unroll
      for (int i = 0; i < 4; i++) z1A[i] = *(const unsigned*)(z1pA + 2*i);
      if (hasB){
        #pragma unroll
        for (int i = 0; i < 4; i++) z1B[i] = *(const unsigned*)(z1pB + 2*i);
      }
      #pragma unroll
      for (int half = 0; half < 2; half++){
        if (half == 1 && !hasB) break;
        const int e0 = half ? e0B : e0A;
        const int r  = half ? rB  : rA;
        const int c0 = half ? cB0 : cA0;
        const uint4 zc4 = half ? zcB : zcA;
        const unsigned* z1w = half ? z1B : z1A;
        const float aa = zcoA[r], cc = zcoC[r];
        const unsigned zw[4] = {zc4.x, zc4.y, zc4.z, zc4.w};
        unsigned ow[4];
        #pragma unroll
        for (int h = 0; h < 4; h++){
          float vL = fmaxf(u2f_lo(z1w[h])*aa + cc, 0.f) + u2f_lo(zw[h]);
          float vH = fmaxf(u2f_hi(z1w[h])*aa + cc, 0.f) + u2f_hi(zw[h]);
          ow[h] = (unsigned)f2bf(vL) | ((unsigned)f2bf(vH) << 16);
        }
        if (c0 == 112){ ow[2] = 0u; ow[3] = 0u; }   // keep pad cols zero
        uint4 o; o.x = ow[0]; o.y = ow[1]; o.z = ow[2]; o.w = ow[3];
        if (with_attn) *(uint4*)(Zb + e0) = o;      // residual write-back (dead after tail)
        *(uint4*)&bBlin[e0] = o;                    // padded staging for downsample
      }
    } else {
      *(uint4*)&bBlin[e0A] = zcA;                   // raw padded Z (pads already 0)
      if (hasB) *(uint4*)&bBlin[e0B] = zcB;
    }
  }
  // X rows on threads 658-773
  {
    float fv = 0.f;
    if (tid >= 658 && tid < 658 + R){
      const int u = tid - 658;
      float* xcr = Xc + ((size_t)b*R + u)*3;
      float v0, v1, v2;
      if (layer > 0){
        float a = xcoA[u], c = xcoC[u];
        const float* x1r = X1 + ((size_t)b*R + u)*3;
        v0 = fmaxf(x1r[0]*a + c, 0.f) + xcr[0];
        v1 = fmaxf(x1r[1]*a + c, 0.f) + xcr[1];
        v2 = fmaxf(x1r[2]*a + c, 0.f) + xcr[2];
        if (with_attn){ xcr[0] = v0; xcr[1] = v1; xcr[2] = v2; }
      } else {
        v0 = xcr[0]; v1 = xcr[1]; v2 = xcr[2];
      }
      if (with_attn){
        const float* aw1l = aw1 + layer * 9;
        const float* ab1l = ab1 + layer * 3;
        #pragma unroll
        for (int o = 0; o < 3; o++)
          Ksm[o*R + u] = ab1l[o] + aw1l[o*3+0]*v0 + aw1l[o*3+1]*v1 + aw1l[o*3+2]*v2;
      }
      float f = fmaxf(dnw[t_snap*3+0]*v0 + dnw[t_snap*3+1]*v1 + dnw[t_snap*3+2]*v2 + dnb[t_snap], 0.f);
      XZ[(size_t)b*XZS + t_snap*R + u] = f2bf(f);
      fv = f;
    }
    if (wave >= 10 && wave <= 12){
      float s = wsum(fv), q = wsum(fv*fv);
      if (lane == 0){ xsred[wave - 10] = s; xqred[wave - 10] = q; }
    }
  }
  // bA pad zeroing (rows 116-127 full; cols 116-135 of rows <116) on threads 774+
  if (tid >= 774){
    for (int i = tid - 774; i < 12*LS; i += 250) bA[116*LS + i] = 0;
    for (int i = tid - 774; i < 116*20; i += 250){
      int r = i/20, c = 116 + (i - r*20);
      bA[r*LS + c] = 0;
    }
  }
  __syncthreads();   // ---- sync1 ----

  // =============== P1: softmax (waves 0-9) || edge downsample (waves 10-15) ===============
  if (wave < 10){
    if (tid == 0){
      atomicAdd(&dnS[sh*10 + t_snap*2+0], xsred[0] + xsred[1] + xsred[2]);
      atomicAdd(&dnS[sh*10 + t_snap*2+1], xqred[0] + xqred[1] + xqred[2]);
    }
    if (with_attn){
      for (int n = wave; n < R; n += 10){
        float k0 = Ksm[n], k1 = Ksm[R+n], k2 = Ksm[2*R+n];
        int m0 = lane, m1 = lane + 64;
        float a0 = k0*Ksm[m0] + k1*Ksm[R+m0] + k2*Ksm[2*R+m0];
        float a1 = (m1 < R) ? (k0*Ksm[m1] + k1*Ksm[R+m1] + k2*Ksm[2*R+m1]) : -1e30f;
        float mx = wmaxr(fmaxf(a0, a1));
        float e0 = __expf(a0 - mx);
        float e1 = (m1 < R) ? __expf(a1 - mx) : 0.f;
        float sm = wsum(e0 + e1);
        float sab = wsum(e0 * ab2l[m0] + ((m1 < R) ? e1 * ab2l[m1] : 0.f));
        float inv = 1.f / sm;
        bA[n*LS + m0] = f2bf(e0 * inv);
        if (m1 < R) bA[n*LS + m1] = f2bf(e1 * inv);
        if (lane == 0) ssm[n] = sab * inv;
      }
    }
  } else {
    const int u = tid - 640;          // 0..383; 348 active
    float f = 0.f;
    if (u < 348){
      int r = u / 3, w = u - 3*r;
      int jlo = (w == 0) ? 39 : 0;
      int jhi = (w == 2) ? 77 : 78;
      int off = (w - 1) * 39;
      const ushort_t* vr = &bBlin[r*RP];
      float acc = 0.f;
      for (int j = jlo; j < jhi; j++) acc += wsm[j] * bf2f(vr[j + off]);
      f = fmaxf(acc + deb[t_snap], 0.f);
      XZ[(size_t)b*XZS + 5*R + t_snap*3*R + r*3 + w] = f2bf(f);
    }
    float s = wsum(f), q = wsum(f*f);
    if (lane == 0){ zds[wave - 10] = s; zqs[wave - 10] = q; }
  }
  __syncthreads();   // ---- sync2 ----

  if (tid == 0){
    float ss = 0.f, qq = 0.f;
    #pragma unroll
    for (int k = 0; k < 6; k++){ ss += zds[k]; qq += zqs[k]; }
    atomicAdd(&deS[sh*10 + t_snap*2+0], ss);
    atomicAdd(&deS[sh*10 + t_snap*2+1], qq);
  }
  if (!with_attn) return;

  // ---- Stage A: W^T-product = aw2^T @ P^T; transposed-packed write -> bB = W row-major ----
  {
    f32x4 acc[4];
    #pragma unroll
    for (int t = 0; t < 4; t++) acc[t] = vzero;
    for (int kk = 0; kk < 128; kk += 32){
      bf16x8 a = *(const bf16x8*)(aw2l + (tr*16 + qm)*128 + kk + quad*8);
      #pragma unroll
      for (int t = 0; t < 4; t++){
        bf16x8 bf = *(const bf16x8*)&bA[((tc0 + t)*16 + qm)*LS + kk + quad*8];
        acc[t] = __builtin_amdgcn_mfma_f32_16x16x32_bf16(a, bf, acc[t], 0, 0, 0);
      }
    }
    const int r0 = tr*16 + quad*4;
    #pragma unroll
    for (int t = 0; t < 4; t++){
      int nn = (tc0 + t)*16 + qm;
      uint2 w;
      w.x = (unsigned)f2bf(acc[t][0]) | ((unsigned)f2bf(acc[t][1]) << 16);
      w.y = (unsigned)f2bf(acc[t][2]) | ((unsigned)f2bf(acc[t][3]) << 16);
      *(uint2*)&bB[nn*LS + r0] = w;
    }
  }
  __syncthreads();

  // ---- Stage B': M^T = W @ Z^T (+ssm); Z fragments = single dwordx4; transposed write -> bA = M ----
  {
    f32x4 acc[4];
    #pragma unroll
    for (int t = 0; t < 4; t++) acc[t] = vzero;
    for (int kk = 0; kk < 128; kk += 32){
      bf16x8 a = *(const bf16x8*)&bB[(tr*16 + qm)*LS + kk + quad*8];
      #pragma unroll
      for (int t = 0; t < 4; t++){
        int nn = (tc0 + t)*16 + qm;
        bf16x8 bf = *(const bf16x8*)(Zb + nn*RP + kk + quad*8);   // 16B-aligned
        acc[t] = __builtin_amdgcn_mfma_f32_16x16x32_bf16(a, bf, acc[t], 0, 0, 0);
      }
    }
    const int r0 = tr*16 + quad*4;
    float s0 = 0.f, s1 = 0.f, s2 = 0.f, s3 = 0.f;
    if (r0 < R){ s0 = ssm[r0]; s1 = ssm[r0+1]; s2 = ssm[r0+2]; s3 = ssm[r0+3]; }
    #pragma unroll
    for (int t = 0; t < 4; t++){
      int nn = (tc0 + t)*16 + qm;
      uint2 w;
      w.x = (unsigned)f2bf(acc[t][0] + s0) | ((unsigned)f2bf(acc[t][1] + s1) << 16);
      w.y = (unsigned)f2bf(acc[t][2] + s2) | ((unsigned)f2bf(acc[t][3] + s3) << 16);
      *(uint2*)&bA[nn*LS + r0] = w;
    }
  }
  __syncthreads();

  // ---- Stage E: E = Z @ ew^T; Z fragments = single dwordx4; transposed write -> bB = E^T ----
  {
    f32x4 acc[4];
    #pragma unroll
    for (int t = 0; t < 4; t++) acc[t] = vzero;
    for (int kk = 0; kk < 128; kk += 32){
      bf16x8 a = *(const bf16x8*)(Zb + (tr*16 + qm)*RP + kk + quad*8);   // 16B-aligned
      #pragma unroll
      for (int t = 0; t < 4; t++){
        bf16x8 bf = *(const bf16x8*)(ewl + ((tc0 + t)*16 + qm)*128 + kk + quad*8);
        acc[t] = __builtin_amdgcn_mfma_f32_16x16x32_bf16(a, bf, acc[t], 0, 0, 0);
      }
    }
    const int r0 = tr*16 + quad*4;
    #pragma unroll
    for (int t = 0; t < 4; t++){
      int nn = (tc0 + t)*16 + qm;
      uint2 w;
      w.x = (unsigned)f2bf(acc[t][0]) | ((unsigned)f2bf(acc[t][1]) << 16);
      w.y = (unsigned)f2bf(acc[t][2]) | ((unsigned)f2bf(acc[t][3]) << 16);
      *(uint2*)&bB[nn*LS + r0] = w;
    }
  }
  __syncthreads();

  // ---- Stage D: Z1 = M @ E + eb -> global bf16 (unpadded); row stats -> LDS partials ----
  {
    f32x4 acc[4];
    #pragma unroll
    for (int t = 0; t < 4; t++) acc[t] = vzero;
    for (int kk = 0; kk < 128; kk += 32){
      bf16x8 a = *(const bf16x8*)&bA[(tr*16 + qm)*LS + kk + quad*8];
      #pragma unroll
      for (int t = 0; t < 4; t++){
        bf16x8 bf = *(const bf16x8*)&bB[((tc0 + t)*16 + qm)*LS + kk + quad*8];
        acc[t] = __builtin_amdgcn_mfma_f32_16x16x32_bf16(a, bf, acc[t], 0, 0, 0);
      }
    }
    float ssv[4] = {0.f,0.f,0.f,0.f}, sqv[4] = {0.f,0.f,0.f,0.f};
    #pragma unroll
    for (int t = 0; t < 4; t++){
      int col = (tc0 + t)*16 + qm;
      float bias = (col < R) ? ebl[col] : 0.f;
      #pragma unroll
      for (int rg = 0; rg < 4; rg++){
        int row = tr*16 + quad*4 + rg;
        float v = (col < R) ? (acc[t][rg] + bias) : 0.f;
        if (col < R && row < R)
          Z1[(size_t)b*RR2 + row*R + col] = f2bf(v);
        ssv[rg] += v; sqv[rg] += v*v;
      }
    }
    #pragma unroll
    for (int off = 1; off < 16; off <<= 1){
      #pragma unroll
      for (int rg = 0; rg < 4; rg++){
        ssv[rg] += __shfl_xor(ssv[rg], off, 64);
        sqv[rg] += __shfl_xor(sqv[rg], off, 64);
      }
    }
    if (qm == 0){
      int half = wave >> 3;
      #pragma unroll
      for (int rg = 0; rg < 4; rg++){
        int row = tr*16 + quad*4 + rg;
        zps[row*2 + half] = ssv[rg];
        zpq[row*2 + half] = sqv[rg];
      }
    }
  }

  // ---- X path partials: T1x = M @ X (M stable in bA); vectorized uint2 LDS reads ----
  const float* Xb = Xc + (size_t)b * R * 3;
  if (tid < R*4){
    int n = tid >> 2, part = tid & 3;
    const ushort_t* rowp = &bA[n*LS];
    float t0 = 0.f, t1 = 0.f, t2 = 0.f;
    for (int mb = part*4; mb < 116; mb += 16){
      uint2 w = *(const uint2*)(rowp + mb);
      float p0 = u2f_lo(w.x), p1 = u2f_hi(w.x), p2 = u2f_lo(w.y), p3 = u2f_hi(w.y);
      const float* x4 = Xb + mb*3;
      t0 = fmaf(p0, x4[0], fmaf(p1, x4[3], fmaf(p2, x4[6], fmaf(p3, x4[9],  t0))));
      t1 = fmaf(p0, x4[1], fmaf(p1, x4[4], fmaf(p2, x4[7], fmaf(p3, x4[10], t1))));
      t2 = fmaf(p0, x4[2], fmaf(p1, x4[5], fmaf(p2, x4[8], fmaf(p3, x4[11], t2))));
    }
    xp[tid*3+0] = t0; xp[tid*3+1] = t1; xp[tid*3+2] = t2;
  }
  __syncthreads();
  if (tid < R){
    float c0 = xp[tid*12+0] + xp[tid*12+3] + xp[tid*12+6] + xp[tid*12+9];
    float c1 = xp[tid*12+1] + xp[tid*12+4] + xp[tid*12+7] + xp[tid*12+10];
    float c2 = xp[tid*12+2] + xp[tid*12+5] + xp[tid*12+8] + xp[tid*12+11];
    float s = 0.f, q = 0.f;
    #pragma unroll
    for (int e = 0; e < 3; e++){
      float v = nbl[e] + c0*nwl[e*3+0] + c1*nwl[e*3+1] + c2*nwl[e*3+2];
      X1[((size_t)b*R + tid)*3 + e] = v;
      s += v; q += v*v;
    }
    atomicAdd(&xsumS[sh*STL + layer*R + tid], s);
    atomicAdd(&xsqS [sh*STL + layer*R + tid], q);
    atomicAdd(&zsumS[sh*STL + layer*R + tid], zps[tid*2] + zps[tid*2+1]);
    atomicAdd(&zsqS [sh*STL + layer*R + tid], zpq[tid*2] + zpq[tid*2+1]);
  }
}

// ---------------- apply BN (in place) to all XZ feature slots, t=0..4, one pass ----------------
__global__ void k_applyAll(const float* __restrict__ dnS, const float* __restrict__ deS,
                           const float* __restrict__ dng, const float* __restrict__ dnbe,
                           const float* __restrict__ deg, const float* __restrict__ debe,
                           ushort_t* __restrict__ XZ)
{
  int idx = blockIdx.x * 256 + threadIdx.x;    // BATCH*R
  int bi = idx / R, r = idx - bi*R;
  const float cn = (float)(BATCH * R);
  const float ce = (float)(BATCH * R * 3);
  #pragma unroll
  for (int t = 0; t < 5; t++){
    float dns = 0.f, dnq = 0.f, des = 0.f, deq = 0.f;
    #pragma unroll
    for (int s2 = 0; s2 < NSH; s2++){
      dns += dnS[s2*10 + t*2+0]; dnq += dnS[s2*10 + t*2+1];
      des += deS[s2*10 + t*2+0]; deq += deS[s2*10 + t*2+1];
    }
    float mn = dns / cn;
    float vn = fmaxf(dnq / cn - mn*mn, 0.f);
    size_t sn = (size_t)bi*XZS + t*R + r;
    float hn = (bf2f(XZ[sn]) - mn) * rsqrtf(vn + EPSF) * dng[t] + dnbe[t];
    XZ[sn] = f2bf(hn);
    float me = des / ce;
    float ve = fmaxf(deq / ce - me*me, 0.f);
    float rse = rsqrtf(ve + EPSF);
    size_t se = (size_t)bi*XZS + 5*R + t*3*R + r*3;
    #pragma unroll
    for (int p = 0; p < 3; p++){
      float he = (bf2f(XZ[se+p]) - me) * rse * deg[t] + debe[t];
      XZ[se+p] = f2bf(he);
    }
  }
}

// ---------------- classifier: fc1 MFMA GEMM with fused fc2 reduction ----------------
__launch_bounds__(256)
__global__ void k_fc(const ushort_t* __restrict__ XZ, const ushort_t* __restrict__ cw1p,
                     const float* __restrict__ cb1, const float* __restrict__ cw2,
                     float* __restrict__ out){
  const int tid  = threadIdx.x;
  const int lane = tid & 63;
  const int wave = tid >> 6;
  const int qm   = lane & 15;
  const int quad = lane >> 4;
  const int m0   = blockIdx.x * 64 + wave * 16;
  const int n0   = blockIdx.y * 64;

  const f32x4 vzero = {0.f, 0.f, 0.f, 0.f};
  f32x4 acc[4];
  #pragma unroll
  for (int t = 0; t < 4; t++) acc[t] = vzero;

  const ushort_t* arow = XZ + (size_t)(m0 + qm) * XZS;
  for (int kk = 0; kk < XZS; kk += 32){
    bf16x8 a = *(const bf16x8*)(arow + kk + quad*8);
    #pragma unroll
    for (int t = 0; t < 4; t++){
      const ushort_t* brow = cw1p + (size_t)(n0 + t*16 + qm) * XZS;
      bf16x8 bf = *(const bf16x8*)(brow + kk + quad*8);
      acc[t] = __builtin_amdgcn_mfma_f32_16x16x32_bf16(a, bf, acc[t], 0, 0, 0);
    }
  }
  // fused fc2: h = relu(acc + cb1); partial dot with cw2 rows; qm-reduce; atomic out
  #pragma unroll
  for (int rg = 0; rg < 4; rg++){
    float p0 = 0.f, p1 = 0.f;
    #pragma unroll
    for (int t = 0; t < 4; t++){
      int n = n0 + t*16 + qm;
      float h = fmaxf(acc[t][rg] + cb1[n], 0.f);
      p0 = fmaf(h, cw2[n], p0);
      p1 = fmaf(h, cw2[1024 + n], p1);
    }
    #pragma unroll
    for (int o = 1; o < 16; o <<= 1){
      p0 += __shfl_xor(p0, o, 64);
      p1 += __shfl_xor(p1, o, 64);
    }
    if (qm == 0){
      int m = m0 + quad*4 + rg;
      atomicAdd(&out[m*2 + 0], p0);
      atomicAdd(&out[m*2 + 1], p1);
    }
  }
}

extern "C" void kernel_launch(void* const* d_in, const int* in_sizes, int n_in,
                              void* d_out, int out_size, void* d_ws, size_t ws_size,
                              hipStream_t stream)
{
  const float* Xin  = (const float*)d_in[0];
  const float* Zin  = (const float*)d_in[1];
  const float* aw1  = (const float*)d_in[2];
  const float* ab1  = (const float*)d_in[3];
  const float* aw2  = (const float*)d_in[4];
  const float* ab2  = (const float*)d_in[5];
  const float* nw   = (const float*)d_in[6];
  const float* nb   = (const float*)d_in[7];
  const float* ew   = (const float*)d_in[8];
  const float* eb   = (const float*)d_in[9];
  const float* gng  = (const float*)d_in[10];
  const float* gnb  = (const float*)d_in[11];
  const float* geg  = (const float*)d_in[12];
  const float* geb  = (const float*)d_in[13];
  const float* dnw  = (const float*)d_in[14];
  const float* dnb  = (const float*)d_in[15];
  const float* dng  = (const float*)d_in[16];
  const float* dnbe = (const float*)d_in[17];
  const float* dew  = (const float*)d_in[18];
  const float* deb  = (const float*)d_in[19];
  const float* deg  = (const float*)d_in[20];
  const float* debe = (const float*)d_in[21];
  const float* cw1  = (const float*)d_in[22];
  const float* cb1  = (const float*)d_in[23];
  const float* cw2  = (const float*)d_in[24];
  const float* cb2  = (const float*)d_in[25];

  // ---- workspace layout (total 68,807,296 B < 69,605,444 B proven addressable) ----
  ushort_t* Zc = (ushort_t*)d_ws;            // bf16 Z state, PADDED rows (RP=120)
  ushort_t* Z1 = Zc + NZP_ELEM;              // bf16 pre-BN Z1 (unpadded; head doubles as guard)
  float*    Xc = (float*)(Z1 + NZ_ELEM);     // fp32 X state
  float*    X1 = Xc + NX_ELEM;               // fp32 pre-BN X1
  ushort_t* XZ = (ushort_t*)(X1 + NX_ELEM);  // bf16 features (B,XZS)
  float*    st = (float*)(XZ + BATCH*XZS);   // stats: 15008 floats (sharded)
  float* zsumS = st;               // [NSH][STL]
  float* zsqS  = st + 3712;
  float* xsumS = st + 7424;
  float* xsqS  = st + 11136;
  float* dnS   = st + 14848;       // [NSH][10]
  float* deS   = st + 14928;       // [NSH][10]
  ushort_t* aw2p = (ushort_t*)(st + 15008);
  ushort_t* ewp  = aw2p + 4*16384;
  ushort_t* cw1p = ewp + 4*16384;

  float* outp = (float*)d_out;

  // merged init (also seeds out = cb2 for the fused-fc atomic accumulation)
  k_init<<<4096, 256, 0, stream>>>(Zin, Zc, Xin, Xc,
                                   st, (unsigned*)XZ, (unsigned*)Z1,
                                   aw2, ew, aw2p, ewp, cw1, cw1p, cb2, outp);

  // fused layers (layer i prologue = BN/residual of layer i-1 + snapshot t=i; then attn i)
  for (int i = 0; i < NL; i++){
    k_fused<<<BATCH, 1024, 0, stream>>>(Xc, Zc, Z1, X1, aw1, ab1, aw2p, ab2,
                                        nw, nb, ewp, eb, zsumS, zsqS, xsumS, xsqS,
                                        geg, geb, gng, gnb, dnw, dnb, dew, deb,
                                        XZ, dnS, deS, i, 1);
  }
  // tail: BN/residual of layer 3 + snapshot t=4, no attention (skips dead Zc/Xc writes)
  k_fused<<<BATCH, 1024, 0, stream>>>(Xc, Zc, Z1, X1, aw1, ab1, aw2p, ab2,
                                      nw, nb, ewp, eb, zsumS, zsqS, xsumS, xsqS,
                                      geg, geb, gng, gnb, dnw, dnb, dew, deb,
                                      XZ, dnS, deS, NL, 0);

  k_applyAll<<<464, 256, 0, stream>>>(dnS, deS, dng, dnbe, deg, debe, XZ);

  k_fc<<<dim3(16, 16), 256, 0, stream>>>(XZ, cw1p, cb1, cw2, outp);
}